// Round 1
// baseline (473.261 us; speedup 1.0000x reference)
//
#include <hip/hip_runtime.h>
#include <math.h>

// ---------------------------------------------------------------------------
// Types / helpers
// ---------------------------------------------------------------------------
typedef __bf16 bf16x8 __attribute__((ext_vector_type(8)));
typedef float floatx4 __attribute__((ext_vector_type(4)));

__device__ __forceinline__ unsigned short f32_to_bf16(float f) {
  unsigned int u = __float_as_uint(f);
  u = u + 0x7FFFu + ((u >> 16) & 1u);   // RNE; inputs finite
  return (unsigned short)(u >> 16);
}
__device__ __forceinline__ float bf16_to_f32(unsigned short s) {
  return __uint_as_float(((unsigned int)s) << 16);
}

// async global->LDS, 16B per lane. lds base must be wave-uniform; HW scatters
// lane i to ldsbase + i*16  [m97 pattern].
__device__ __forceinline__ void gld_lds16(const unsigned short* g,
                                          unsigned short* l) {
  __builtin_amdgcn_global_load_lds(
      (const __attribute__((address_space(1))) unsigned int*)g,
      (__attribute__((address_space(3))) unsigned int*)l, 16, 0, 0);
}

// ---------------------------------------------------------------------------
// fp32 -> bf16 cast (vectorized float4 -> ushort4)
// ---------------------------------------------------------------------------
__global__ void cast_kernel(const float* __restrict__ in,
                            unsigned short* __restrict__ out, int n4) {
  int i = blockIdx.x * blockDim.x + threadIdx.x;
  if (i >= n4) return;
  const float4 v = reinterpret_cast<const float4*>(in)[i];
  ushort4 o;
  o.x = f32_to_bf16(v.x); o.y = f32_to_bf16(v.y);
  o.z = f32_to_bf16(v.z); o.w = f32_to_bf16(v.w);
  reinterpret_cast<ushort4*>(out)[i] = o;
}

// 4 equal-size weight casts in one dispatch (blockIdx.y selects buffer)
__global__ void cast4_kernel(const float* __restrict__ a,
                             const float* __restrict__ b,
                             const float* __restrict__ c,
                             const float* __restrict__ d,
                             unsigned short* __restrict__ oa,
                             unsigned short* __restrict__ ob,
                             unsigned short* __restrict__ oc,
                             unsigned short* __restrict__ od, int n4) {
  int i = blockIdx.x * blockDim.x + threadIdx.x;
  if (i >= n4) return;
  const float* in;
  unsigned short* out;
  switch (blockIdx.y) {
    case 0: in = a; out = oa; break;
    case 1: in = b; out = ob; break;
    case 2: in = c; out = oc; break;
    default: in = d; out = od; break;
  }
  const float4 v = reinterpret_cast<const float4*>(in)[i];
  ushort4 o;
  o.x = f32_to_bf16(v.x); o.y = f32_to_bf16(v.y);
  o.z = f32_to_bf16(v.z); o.w = f32_to_bf16(v.w);
  reinterpret_cast<ushort4*>(out)[i] = o;
}

// ---------------------------------------------------------------------------
// RoPE cos/sin table: tab[s*64+i] = (cos, sin) of s / 10000^(i/64)
// ---------------------------------------------------------------------------
__global__ void rope_table_kernel(float2* __restrict__ tab, int total) {
  int idx = blockIdx.x * blockDim.x + threadIdx.x;
  if (idx >= total) return;
  const int s = idx >> 6, i = idx & 63;
  const float inv = powf(10000.0f, -(float)i * (1.0f / 64.0f));
  const float ang = (float)s * inv;
  tab[idx] = make_float2(cosf(ang), sinf(ang));
}

// ---------------------------------------------------------------------------
// Fused GEMM: C[m][n] = sum_k A[m][k]*B[n][k] + bias[n]
// 128x128 tile, BK=64, 4 waves, 4x4 16x16x32. Staging via global_load_lds
// width=16 into UNPADDED LDS with XOR chunk swizzle on the GLOBAL address.
// EPI=0: fp32 out + bias (used for the O projection).
// ---------------------------------------------------------------------------
template <int EPI>
__global__ __launch_bounds__(256) void gemm_fused(
    const unsigned short* __restrict__ A, const unsigned short* __restrict__ B,
    const float* __restrict__ bias, float* __restrict__ Cf,
    unsigned short* __restrict__ Cb, const float2* __restrict__ tab,
    float scl, int M, int N, int K, int S) {
  __shared__ unsigned short As[128 * 64];
  __shared__ unsigned short Bs[128 * 64];
  const int t = threadIdx.x;
  const int lane = t & 63;
  const int w = t >> 6;
  const int bm = blockIdx.y * 128;
  const int bn = blockIdx.x * 128;
  const int wm = (w & 1) * 64;
  const int wn = (w >> 1) * 64;
  const int m16 = lane & 15;
  const int quad = lane >> 4;
  const int key = m16 & 7;

  const int lr = lane >> 3;
  const int lc = ((lane & 7) ^ lr) * 8;

  floatx4 acc[4][4];
#pragma unroll
  for (int i = 0; i < 4; ++i)
#pragma unroll
    for (int j = 0; j < 4; ++j) acc[i][j] = floatx4{0.f, 0.f, 0.f, 0.f};

  const unsigned short* Abase = A + (size_t)(bm + w * 32 + lr) * K + lc;
  const unsigned short* Bbase = B + (size_t)(bn + w * 32 + lr) * K + lc;

  for (int k0 = 0; k0 < K; k0 += 64) {
    __syncthreads();
#pragma unroll
    for (int it = 0; it < 4; ++it) {
      gld_lds16(Abase + (size_t)it * 8 * K + k0, &As[(w * 4 + it) * 512]);
      gld_lds16(Bbase + (size_t)it * 8 * K + k0, &Bs[(w * 4 + it) * 512]);
    }
    __syncthreads();
#pragma unroll
    for (int ks = 0; ks < 64; ks += 32) {
      const int ck = ks >> 3;
      bf16x8 af[4], bfr[4];
#pragma unroll
      for (int i = 0; i < 4; ++i)
        af[i] = *reinterpret_cast<const bf16x8*>(
            &As[(wm + i * 16 + m16) * 64 + ((ck | quad) ^ key) * 8]);
#pragma unroll
      for (int j = 0; j < 4; ++j)
        bfr[j] = *reinterpret_cast<const bf16x8*>(
            &Bs[(wn + j * 16 + m16) * 64 + ((ck | quad) ^ key) * 8]);
#pragma unroll
      for (int i = 0; i < 4; ++i)
#pragma unroll
        for (int j = 0; j < 4; ++j)
          acc[i][j] = __builtin_amdgcn_mfma_f32_16x16x32_bf16(
              af[i], bfr[j], acc[i][j], 0, 0, 0);
    }
  }

#pragma unroll
  for (int i = 0; i < 4; ++i) {
    const int rbase = bm + wm + i * 16 + quad * 4;
#pragma unroll
    for (int j = 0; j < 4; ++j) {
      const int col = bn + wn + j * 16 + m16;
      const float bvv = bias[col];
      if (EPI == 0) {
#pragma unroll
        for (int r = 0; r < 4; ++r)
          Cf[(size_t)(rbase + r) * N + col] = acc[i][j][r] + bvv;
      }
    }
  }
}

// ---------------------------------------------------------------------------
// QKV fused projection: one dispatch, blockIdx.z in {0,1,2} selects
// {Wq->Q(RoPE,scaled), Wk->K(RoPE), Wv->Vt(transposed bf16)}.
// Same inner loop as gemm_fused; 3x the in-flight blocks (1536) so the
// barrier-drain stall of one block hides under another's compute.
// ---------------------------------------------------------------------------
__global__ __launch_bounds__(256) void gemm_qkv(
    const unsigned short* __restrict__ A, const unsigned short* __restrict__ Bq,
    const unsigned short* __restrict__ Bk, const unsigned short* __restrict__ Bv,
    const float* __restrict__ biasq, const float* __restrict__ biask,
    const float* __restrict__ biasv, unsigned short* __restrict__ Qb,
    unsigned short* __restrict__ Kb, unsigned short* __restrict__ Vtb,
    const float2* __restrict__ tab, float qscale, int M, int N, int K, int S) {
  __shared__ unsigned short As[128 * 64];
  __shared__ unsigned short Bs[128 * 64];
  const int t = threadIdx.x;
  const int lane = t & 63;
  const int w = t >> 6;
  const int z = blockIdx.z;
  const int bm = blockIdx.y * 128;
  const int bn = blockIdx.x * 128;
  const int wm = (w & 1) * 64;
  const int wn = (w >> 1) * 64;
  const int m16 = lane & 15;
  const int quad = lane >> 4;
  const int key = m16 & 7;

  const int lr = lane >> 3;
  const int lc = ((lane & 7) ^ lr) * 8;

  const unsigned short* B = (z == 0) ? Bq : ((z == 1) ? Bk : Bv);
  const float* bias = (z == 0) ? biasq : ((z == 1) ? biask : biasv);
  unsigned short* Cb = (z == 0) ? Qb : ((z == 1) ? Kb : Vtb);
  const float scl = (z == 0) ? qscale : 1.0f;

  floatx4 acc[4][4];
#pragma unroll
  for (int i = 0; i < 4; ++i)
#pragma unroll
    for (int j = 0; j < 4; ++j) acc[i][j] = floatx4{0.f, 0.f, 0.f, 0.f};

  const unsigned short* Abase = A + (size_t)(bm + w * 32 + lr) * K + lc;
  const unsigned short* Bbase = B + (size_t)(bn + w * 32 + lr) * K + lc;

  for (int k0 = 0; k0 < K; k0 += 64) {
    __syncthreads();
#pragma unroll
    for (int it = 0; it < 4; ++it) {
      gld_lds16(Abase + (size_t)it * 8 * K + k0, &As[(w * 4 + it) * 512]);
      gld_lds16(Bbase + (size_t)it * 8 * K + k0, &Bs[(w * 4 + it) * 512]);
    }
    __syncthreads();
#pragma unroll
    for (int ks = 0; ks < 64; ks += 32) {
      const int ck = ks >> 3;
      bf16x8 af[4], bfr[4];
#pragma unroll
      for (int i = 0; i < 4; ++i)
        af[i] = *reinterpret_cast<const bf16x8*>(
            &As[(wm + i * 16 + m16) * 64 + ((ck | quad) ^ key) * 8]);
#pragma unroll
      for (int j = 0; j < 4; ++j)
        bfr[j] = *reinterpret_cast<const bf16x8*>(
            &Bs[(wn + j * 16 + m16) * 64 + ((ck | quad) ^ key) * 8]);
#pragma unroll
      for (int i = 0; i < 4; ++i)
#pragma unroll
        for (int j = 0; j < 4; ++j)
          acc[i][j] = __builtin_amdgcn_mfma_f32_16x16x32_bf16(
              af[i], bfr[j], acc[i][j], 0, 0, 0);
    }
  }

  // epilogue: C/D layout col=lane&15, row=quad*4+reg  [m89/m91 verified]
#pragma unroll
  for (int i = 0; i < 4; ++i) {
    const int rbase = bm + wm + i * 16 + quad * 4;
#pragma unroll
    for (int j = 0; j < 4; ++j) {
      const int col = bn + wn + j * 16 + m16;
      const float bvv = bias[col];
      if (z != 2) {  // RoPE (interleaved pairs) -> bf16, scaled
        const int pi = (col & 127) >> 1;
#pragma unroll
        for (int r = 0; r < 4; ++r) {
          const int row = rbase + r;
          const int s = row & (S - 1);
          const float v = acc[i][j][r] + bvv;
          const float vp = __shfl_xor(v, 1);
          const float2 cs = tab[s * 64 + pi];
          const float oe = (v * cs.x - vp * cs.y) * scl;
          const float oo = (vp * cs.x + v * cs.y) * scl;
          if ((m16 & 1) == 0) {
            const unsigned pk =
                (unsigned)f32_to_bf16(oe) | ((unsigned)f32_to_bf16(oo) << 16);
            *reinterpret_cast<unsigned*>(Cb + (size_t)row * N + col) = pk;
          }
        }
      } else {  // transposed bf16 V: Vt[(b*2048 + col)][s]
        const int b = rbase >> 11;           // S = 2048
        const int s = rbase & (S - 1);       // multiple of 4
        ushort4 pk;
        pk.x = f32_to_bf16(acc[i][j][0] + bvv);
        pk.y = f32_to_bf16(acc[i][j][1] + bvv);
        pk.z = f32_to_bf16(acc[i][j][2] + bvv);
        pk.w = f32_to_bf16(acc[i][j][3] + bvv);
        *reinterpret_cast<ushort4*>(
            Cb + ((size_t)((b << 11) + col)) * S + s) = pk;
      }
    }
  }
}

// ---------------------------------------------------------------------------
// MFMA flash attention with T14 async-STAGE split: next tile's K/V global
// loads are issued right after the staging barrier (into regs) and written to
// LDS at the next iteration's top -- HBM latency hides under MFMA+softmax.
// ---------------------------------------------------------------------------
constexpr int F_BQ = 128, F_BK = 64, F_DH = 128;
constexpr int KS_STR = 136;
constexpr int VS_STR = 72;
constexpr int PS_STR = 72;

__global__ __launch_bounds__(256, 2) void fattn_kernel(
    const unsigned short* __restrict__ Qb, const unsigned short* __restrict__ Kb,
    const unsigned short* __restrict__ Vtb, unsigned short* __restrict__ Ob,
    int S, int H, int nh) {
  __shared__ unsigned short Ks[F_BK * KS_STR];
  __shared__ unsigned short Vts[F_DH * VS_STR];
  __shared__ unsigned short Ps[F_BQ * PS_STR];

  const int t = threadIdx.x;
  const int lane = t & 63;
  const int w = t >> 6;
  const int l15 = lane & 15;
  const int quad = lane >> 4;

  const int i = blockIdx.x;
  const int bh = i & 31;
  const int qt = (i < 256) ? (i >> 5) : (15 - ((i - 256) >> 5));
  const int h = bh & 15;
  const int b = bh >> 4;
  const int q0 = qt * F_BQ;

  const unsigned short* Qrow = Qb + ((size_t)(b * S + q0)) * H + h * F_DH;
  const unsigned short* Krow = Kb + ((size_t)b * S) * H + h * F_DH;
  const unsigned short* Vtrow = Vtb + ((size_t)bh * F_DH) * S;
  unsigned short* Orow = Ob + ((size_t)(b * S + q0)) * H + h * F_DH;

  // staging geometry (per-thread, fixed across tiles)
  const int kt = t >> 2, ck0 = (t & 3) * 32;      // K: row kt (64), 32 cols
  const int vd = t >> 1, cv0 = (t & 1) * 32;      // Vt: row vd (128), 32 cols
  const unsigned short* Kg = Krow + (size_t)kt * H + ck0;
  const unsigned short* Vg = Vtrow + (size_t)vd * S + cv0;

  bf16x8 aq[2][4];
#pragma unroll
  for (int qg = 0; qg < 2; ++qg)
#pragma unroll
    for (int ks = 0; ks < 4; ++ks)
      aq[qg][ks] = *reinterpret_cast<const bf16x8*>(
          Qrow + (size_t)(w * 32 + qg * 16 + l15) * H + ks * 32 + quad * 8);

  // prologue: tile 0 K/V into regs
  uint4 kreg[4], vreg[4];
#pragma unroll
  for (int ii = 0; ii < 4; ++ii)
    kreg[ii] = *reinterpret_cast<const uint4*>(Kg + ii * 8);
#pragma unroll
  for (int ii = 0; ii < 4; ++ii)
    vreg[ii] = *reinterpret_cast<const uint4*>(Vg + ii * 8);

  floatx4 oacc[2][8];
#pragma unroll
  for (int qg = 0; qg < 2; ++qg)
#pragma unroll
    for (int dj = 0; dj < 8; ++dj) oacc[qg][dj] = floatx4{0.f, 0.f, 0.f, 0.f};
  float lpart[2][4] = {{0.f, 0.f, 0.f, 0.f}, {0.f, 0.f, 0.f, 0.f}};
  int qrow[2][4];
#pragma unroll
  for (int qg = 0; qg < 2; ++qg)
#pragma unroll
    for (int r = 0; r < 4; ++r)
      qrow[qg][r] = q0 + w * 32 + qg * 16 + quad * 4 + r;

  const int ntile = q0 / F_BK + 2;
  for (int tile = 0; tile < ntile; ++tile) {
    const int k0 = tile * F_BK;
    __syncthreads();  // previous-tile readers done
#pragma unroll
    for (int ii = 0; ii < 4; ++ii)
      *reinterpret_cast<uint4*>(&Ks[kt * KS_STR + ck0 + ii * 8]) = kreg[ii];
#pragma unroll
    for (int ii = 0; ii < 4; ++ii)
      *reinterpret_cast<uint4*>(&Vts[vd * VS_STR + cv0 + ii * 8]) = vreg[ii];
    __syncthreads();  // LDS data visible

    // issue next tile's loads NOW; they complete under this tile's compute
    if (tile + 1 < ntile) {
      const int k1 = (tile + 1) * F_BK;
#pragma unroll
      for (int ii = 0; ii < 4; ++ii)
        kreg[ii] = *reinterpret_cast<const uint4*>(Kg + (size_t)k1 * H + ii * 8);
#pragma unroll
      for (int ii = 0; ii < 4; ++ii)
        vreg[ii] = *reinterpret_cast<const uint4*>(Vg + k1 + ii * 8);
    }

    floatx4 sacc[2][4];
#pragma unroll
    for (int qg = 0; qg < 2; ++qg)
#pragma unroll
      for (int j = 0; j < 4; ++j) sacc[qg][j] = floatx4{0.f, 0.f, 0.f, 0.f};
#pragma unroll
    for (int j = 0; j < 4; ++j) {
      bf16x8 bk[4];
#pragma unroll
      for (int ks = 0; ks < 4; ++ks)
        bk[ks] = *reinterpret_cast<const bf16x8*>(
            &Ks[(j * 16 + l15) * KS_STR + ks * 32 + quad * 8]);
#pragma unroll
      for (int qg = 0; qg < 2; ++qg)
#pragma unroll
        for (int ks = 0; ks < 4; ++ks)
          sacc[qg][j] = __builtin_amdgcn_mfma_f32_16x16x32_bf16(
              aq[qg][ks], bk[ks], sacc[qg][j], 0, 0, 0);
    }

#pragma unroll
    for (int qg = 0; qg < 2; ++qg)
#pragma unroll
      for (int j = 0; j < 4; ++j) {
        const int ktg = k0 + j * 16 + l15;
#pragma unroll
        for (int r = 0; r < 4; ++r) {
          const float p =
              (ktg <= qrow[qg][r]) ? exp2f(sacc[qg][j][r]) : 0.0f;
          lpart[qg][r] += p;
          Ps[(w * 32 + qg * 16 + quad * 4 + r) * PS_STR + j * 16 + l15] =
              f32_to_bf16(p);
        }
      }

#pragma unroll
    for (int ks2 = 0; ks2 < 2; ++ks2) {
      bf16x8 ap[2];
#pragma unroll
      for (int qg = 0; qg < 2; ++qg)
        ap[qg] = *reinterpret_cast<const bf16x8*>(
            &Ps[(w * 32 + qg * 16 + l15) * PS_STR + ks2 * 32 + quad * 8]);
#pragma unroll
      for (int dj = 0; dj < 8; ++dj) {
        const bf16x8 bv = *reinterpret_cast<const bf16x8*>(
            &Vts[(dj * 16 + l15) * VS_STR + ks2 * 32 + quad * 8]);
#pragma unroll
        for (int qg = 0; qg < 2; ++qg)
          oacc[qg][dj] = __builtin_amdgcn_mfma_f32_16x16x32_bf16(
              ap[qg], bv, oacc[qg][dj], 0, 0, 0);
      }
    }
  }

#pragma unroll
  for (int qg = 0; qg < 2; ++qg)
#pragma unroll
    for (int r = 0; r < 4; ++r) {
      float l = lpart[qg][r];
      l += __shfl_xor(l, 1);
      l += __shfl_xor(l, 2);
      l += __shfl_xor(l, 4);
      l += __shfl_xor(l, 8);
      const float linv = 1.0f / l;
      unsigned short* orow =
          Orow + (size_t)(w * 32 + qg * 16 + quad * 4 + r) * H;
#pragma unroll
      for (int dj = 0; dj < 8; ++dj)
        orow[dj * 16 + l15] = f32_to_bf16(oacc[qg][dj][r] * linv);
    }
}

// ---------------------------------------------------------------------------
// Launch
// ---------------------------------------------------------------------------
extern "C" void kernel_launch(void* const* d_in, const int* in_sizes, int n_in,
                              void* d_out, int out_size, void* d_ws,
                              size_t ws_size, hipStream_t stream) {
  const float* x  = (const float*)d_in[0];
  const float* Wq = (const float*)d_in[1];
  const float* bq = (const float*)d_in[2];
  const float* Wk = (const float*)d_in[3];
  const float* bk = (const float*)d_in[4];
  const float* Wv = (const float*)d_in[5];
  const float* bv = (const float*)d_in[6];
  const float* Wo = (const float*)d_in[7];
  const float* bo = (const float*)d_in[8];
  float* out = (float*)d_out;

  const int B = 2, S = 2048, H = 2048, nh = 16;
  const int M = B * S;  // 4096

  // workspace layout (~113 MB, no overlays)
  unsigned short* Wqb = (unsigned short*)d_ws;
  unsigned short* Wkb = Wqb + (size_t)H * H;
  unsigned short* Wvb = Wkb + (size_t)H * H;
  unsigned short* Wob = Wvb + (size_t)H * H;
  unsigned short* xb  = Wob + (size_t)H * H;
  unsigned short* Qbb = xb + (size_t)M * H;
  unsigned short* Kbb = Qbb + (size_t)M * H;
  unsigned short* Vtb = Kbb + (size_t)M * H;
  unsigned short* Ob  = Vtb + (size_t)M * H;
  float2* tab = (float2*)(Ob + (size_t)M * H);  // S*64 float2 = 1 MB

  const int cast_w4 = H * H / 4;
  const int cast_x4 = M * H / 4;
  const int tab_n = S * 64;

  rope_table_kernel<<<dim3(tab_n / 256), dim3(256), 0, stream>>>(tab, tab_n);
  cast_kernel<<<dim3(cast_x4 / 256), dim3(256), 0, stream>>>(x, xb, cast_x4);
  cast4_kernel<<<dim3(cast_w4 / 256, 4), dim3(256), 0, stream>>>(
      Wq, Wk, Wv, Wo, Wqb, Wkb, Wvb, Wob, cast_w4);

  const float qscale = 0.08838834764831845f * 1.4426950408889634f;

  // Q, K, V projections in ONE dispatch: (16, 32, 3) = 1536 blocks
  gemm_qkv<<<dim3(H / 128, M / 128, 3), dim3(256), 0, stream>>>(
      xb, Wqb, Wkb, Wvb, bq, bk, bv, Qbb, Kbb, Vtb, tab, qscale, M, H, H, S);

  fattn_kernel<<<dim3((S / F_BQ) * B * nh), dim3(256), 0, stream>>>(
      Qbb, Kbb, Vtb, Ob, S, H, nh);

  gemm_fused<0><<<dim3(H / 128, M / 128), dim3(256), 0, stream>>>(
      Ob, Wob, bo, out, nullptr, nullptr, 1.0f, M, H, H, S);
}

// Round 4
// 435.500 us; speedup vs baseline: 1.0867x; 1.0867x over previous
//
#include <hip/hip_runtime.h>
#include <math.h>

// ---------------------------------------------------------------------------
// Types / helpers
// ---------------------------------------------------------------------------
typedef __bf16 bf16x8 __attribute__((ext_vector_type(8)));
typedef float floatx4 __attribute__((ext_vector_type(4)));

__device__ __forceinline__ unsigned short f32_to_bf16(float f) {
  unsigned int u = __float_as_uint(f);
  u = u + 0x7FFFu + ((u >> 16) & 1u);   // RNE; inputs finite
  return (unsigned short)(u >> 16);
}
__device__ __forceinline__ float bf16_to_f32(unsigned short s) {
  return __uint_as_float(((unsigned int)s) << 16);
}

// async global->LDS, 16B per lane. lds base must be wave-uniform; HW scatters
// lane i to ldsbase + i*16  [m97 pattern].
__device__ __forceinline__ void gld_lds16(const unsigned short* g,
                                          unsigned short* l) {
  __builtin_amdgcn_global_load_lds(
      (const __attribute__((address_space(1))) unsigned int*)g,
      (__attribute__((address_space(3))) unsigned int*)l, 16, 0, 0);
}

// ---------------------------------------------------------------------------
// fp32 -> bf16 cast (vectorized float4 -> ushort4)
// ---------------------------------------------------------------------------
__global__ void cast_kernel(const float* __restrict__ in,
                            unsigned short* __restrict__ out, int n4) {
  int i = blockIdx.x * blockDim.x + threadIdx.x;
  if (i >= n4) return;
  const float4 v = reinterpret_cast<const float4*>(in)[i];
  ushort4 o;
  o.x = f32_to_bf16(v.x); o.y = f32_to_bf16(v.y);
  o.z = f32_to_bf16(v.z); o.w = f32_to_bf16(v.w);
  reinterpret_cast<ushort4*>(out)[i] = o;
}

// 4 equal-size weight casts in one dispatch (blockIdx.y selects buffer);
// per-element identical to cast_kernel (bit-exact, no shared writes).
__global__ void cast4_kernel(const float* __restrict__ a,
                             const float* __restrict__ b,
                             const float* __restrict__ c,
                             const float* __restrict__ d,
                             unsigned short* __restrict__ oa,
                             unsigned short* __restrict__ ob,
                             unsigned short* __restrict__ oc,
                             unsigned short* __restrict__ od, int n4) {
  int i = blockIdx.x * blockDim.x + threadIdx.x;
  if (i >= n4) return;
  const float* in;
  unsigned short* out;
  switch (blockIdx.y) {
    case 0: in = a; out = oa; break;
    case 1: in = b; out = ob; break;
    case 2: in = c; out = oc; break;
    default: in = d; out = od; break;
  }
  const float4 v = reinterpret_cast<const float4*>(in)[i];
  ushort4 o;
  o.x = f32_to_bf16(v.x); o.y = f32_to_bf16(v.y);
  o.z = f32_to_bf16(v.z); o.w = f32_to_bf16(v.w);
  reinterpret_cast<ushort4*>(out)[i] = o;
}

// ---------------------------------------------------------------------------
// RoPE cos/sin table: tab[s*64+i] = (cos, sin) of s / 10000^(i/64)
// ---------------------------------------------------------------------------
__global__ void rope_table_kernel(float2* __restrict__ tab, int total) {
  int idx = blockIdx.x * blockDim.x + threadIdx.x;
  if (idx >= total) return;
  const int s = idx >> 6, i = idx & 63;
  const float inv = powf(10000.0f, -(float)i * (1.0f / 64.0f));
  const float ang = (float)s * inv;
  tab[idx] = make_float2(cosf(ang), sinf(ang));
}

// ---------------------------------------------------------------------------
// Fused GEMM: C[m][n] = sum_k A[m][k]*B[n][k] + bias[n]
// A: MxK bf16 rm, B: NxK bf16 rm. 128x128 tile, BK=64, 4 waves, 4x4 16x16x32.
// Verbatim round-0 kernel except: XCD-aware bijective block swizzle (requires
// gridDim.x*gridDim.y % 8 == 0; true for all uses here: 512 blocks). The
// swizzle only remaps block->tile; per-tile math unchanged (bit-identical).
// EPI=0: fp32 out + bias.
// EPI=1: bias + RoPE (interleaved pairs, table lookup) -> bf16, scaled by scl.
// EPI=2: bias -> bf16 transposed Vt[(b*16 + col/128)*128 + col%128][s].
// ---------------------------------------------------------------------------
template <int EPI>
__global__ __launch_bounds__(256) void gemm_fused(
    const unsigned short* __restrict__ A, const unsigned short* __restrict__ B,
    const float* __restrict__ bias, float* __restrict__ Cf,
    unsigned short* __restrict__ Cb, const float2* __restrict__ tab,
    float scl, int M, int N, int K, int S) {
  __shared__ unsigned short As[128 * 64];
  __shared__ unsigned short Bs[128 * 64];
  const int t = threadIdx.x;
  const int lane = t & 63;
  const int w = t >> 6;

  // XCD swizzle: blocks orig%8 land on XCD orig%8 (round-robin dispatch);
  // give each XCD a contiguous tile range -> A-panel L2 locality.
  const int nwg = gridDim.x * gridDim.y;       // 512 here; 512 % 8 == 0
  const int orig = blockIdx.y * gridDim.x + blockIdx.x;
  const int wgid = (orig & 7) * (nwg >> 3) + (orig >> 3);
  const int bm = (wgid / gridDim.x) * 128;
  const int bn = (wgid % gridDim.x) * 128;

  const int wm = (w & 1) * 64;
  const int wn = (w >> 1) * 64;
  const int m16 = lane & 15;
  const int quad = lane >> 4;
  const int key = m16 & 7;

  // staging geometry: chunk ch = w*4+it covers LDS rows [ch*8, ch*8+8).
  // lane -> row ch*8 + lane/8, global col chunk (lane%8) ^ (lane/8)  (swizzle)
  const int lr = lane >> 3;
  const int lc = ((lane & 7) ^ lr) * 8;

  floatx4 acc[4][4];
#pragma unroll
  for (int i = 0; i < 4; ++i)
#pragma unroll
    for (int j = 0; j < 4; ++j) acc[i][j] = floatx4{0.f, 0.f, 0.f, 0.f};

  const unsigned short* Abase = A + (size_t)(bm + w * 32 + lr) * K + lc;
  const unsigned short* Bbase = B + (size_t)(bn + w * 32 + lr) * K + lc;

  for (int k0 = 0; k0 < K; k0 += 64) {
    __syncthreads();  // previous-iter readers done before overwrite
#pragma unroll
    for (int it = 0; it < 4; ++it) {
      gld_lds16(Abase + (size_t)it * 8 * K + k0, &As[(w * 4 + it) * 512]);
      gld_lds16(Bbase + (size_t)it * 8 * K + k0, &Bs[(w * 4 + it) * 512]);
    }
    __syncthreads();  // drains vmcnt(0): LDS data visible
#pragma unroll
    for (int ks = 0; ks < 64; ks += 32) {
      const int ck = ks >> 3;  // 0 or 4
      bf16x8 af[4], bfr[4];
#pragma unroll
      for (int i = 0; i < 4; ++i)
        af[i] = *reinterpret_cast<const bf16x8*>(
            &As[(wm + i * 16 + m16) * 64 + ((ck | quad) ^ key) * 8]);
#pragma unroll
      for (int j = 0; j < 4; ++j)
        bfr[j] = *reinterpret_cast<const bf16x8*>(
            &Bs[(wn + j * 16 + m16) * 64 + ((ck | quad) ^ key) * 8]);
#pragma unroll
      for (int i = 0; i < 4; ++i)
#pragma unroll
        for (int j = 0; j < 4; ++j)
          acc[i][j] = __builtin_amdgcn_mfma_f32_16x16x32_bf16(
              af[i], bfr[j], acc[i][j], 0, 0, 0);
    }
  }

  // epilogue: C/D layout col=lane&15, row=quad*4+reg  [m89/m91 verified]
#pragma unroll
  for (int i = 0; i < 4; ++i) {
    const int rbase = bm + wm + i * 16 + quad * 4;
#pragma unroll
    for (int j = 0; j < 4; ++j) {
      const int col = bn + wn + j * 16 + m16;
      const float bv = bias[col];
      if (EPI == 0) {
#pragma unroll
        for (int r = 0; r < 4; ++r)
          Cf[(size_t)(rbase + r) * N + col] = acc[i][j][r] + bv;
      } else if (EPI == 1) {
        const int pi = (col & 127) >> 1;
#pragma unroll
        for (int r = 0; r < 4; ++r) {
          const int row = rbase + r;
          const int s = row & (S - 1);
          const float v = acc[i][j][r] + bv;
          const float vp = __shfl_xor(v, 1);
          const float2 cs = tab[s * 64 + pi];
          // even lane holds x_even (v), partner x_odd (vp); computes both
          const float oe = (v * cs.x - vp * cs.y) * scl;
          const float oo = (vp * cs.x + v * cs.y) * scl;
          if ((m16 & 1) == 0) {
            const unsigned pk =
                (unsigned)f32_to_bf16(oe) | ((unsigned)f32_to_bf16(oo) << 16);
            *reinterpret_cast<unsigned*>(Cb + (size_t)row * N + col) = pk;
          }
        }
      } else {  // EPI == 2: transposed bf16 V
        const int b = rbase >> 11;           // S = 2048
        const int s = rbase & (S - 1);       // multiple of 4
        ushort4 pk;
        pk.x = f32_to_bf16(acc[i][j][0] + bv);
        pk.y = f32_to_bf16(acc[i][j][1] + bv);
        pk.z = f32_to_bf16(acc[i][j][2] + bv);
        pk.w = f32_to_bf16(acc[i][j][3] + bv);
        *reinterpret_cast<ushort4*>(
            Cb + ((size_t)((b << 11) + col)) * S + s) = pk;
      }
    }
  }
}

// ---------------------------------------------------------------------------
// MFMA flash attention — VERBATIM round-0 kernel (verified: 104 us, absmax
// 0.0156). Do not touch until the accuracy-drift mystery is resolved.
// ---------------------------------------------------------------------------
constexpr int F_BQ = 128, F_BK = 64, F_DH = 128;
constexpr int KS_STR = 136;
constexpr int VS_STR = 72;
constexpr int PS_STR = 72;

__global__ __launch_bounds__(256, 2) void fattn_kernel(
    const unsigned short* __restrict__ Qb, const unsigned short* __restrict__ Kb,
    const unsigned short* __restrict__ Vtb, unsigned short* __restrict__ Ob,
    int S, int H, int nh) {
  __shared__ unsigned short Ks[F_BK * KS_STR];
  __shared__ unsigned short Vts[F_DH * VS_STR];
  __shared__ unsigned short Ps[F_BQ * PS_STR];

  const int t = threadIdx.x;
  const int lane = t & 63;
  const int w = t >> 6;
  const int l15 = lane & 15;
  const int quad = lane >> 4;

  const int i = blockIdx.x;
  const int bh = i & 31;
  const int qt = (i < 256) ? (i >> 5) : (15 - ((i - 256) >> 5));
  const int h = bh & 15;
  const int b = bh >> 4;
  const int q0 = qt * F_BQ;

  const unsigned short* Qrow = Qb + ((size_t)(b * S + q0)) * H + h * F_DH;
  const unsigned short* Krow = Kb + ((size_t)b * S) * H + h * F_DH;
  const unsigned short* Vtrow = Vtb + ((size_t)bh * F_DH) * S;
  unsigned short* Orow = Ob + ((size_t)(b * S + q0)) * H + h * F_DH;

  bf16x8 aq[2][4];
#pragma unroll
  for (int qg = 0; qg < 2; ++qg)
#pragma unroll
    for (int ks = 0; ks < 4; ++ks)
      aq[qg][ks] = *reinterpret_cast<const bf16x8*>(
          Qrow + (size_t)(w * 32 + qg * 16 + l15) * H + ks * 32 + quad * 8);

  floatx4 oacc[2][8];
#pragma unroll
  for (int qg = 0; qg < 2; ++qg)
#pragma unroll
    for (int dj = 0; dj < 8; ++dj) oacc[qg][dj] = floatx4{0.f, 0.f, 0.f, 0.f};
  float lpart[2][4] = {{0.f, 0.f, 0.f, 0.f}, {0.f, 0.f, 0.f, 0.f}};
  int qrow[2][4];
#pragma unroll
  for (int qg = 0; qg < 2; ++qg)
#pragma unroll
    for (int r = 0; r < 4; ++r)
      qrow[qg][r] = q0 + w * 32 + qg * 16 + quad * 4 + r;

  const int ntile = q0 / F_BK + 2;
  for (int tile = 0; tile < ntile; ++tile) {
    const int k0 = tile * F_BK;
    __syncthreads();
    {
      const int kt = t >> 2, c0 = (t & 3) * 32;
      const unsigned short* g = Krow + (size_t)(k0 + kt) * H + c0;
#pragma unroll
      for (int ii = 0; ii < 4; ++ii)
        *reinterpret_cast<uint4*>(&Ks[kt * KS_STR + c0 + ii * 8]) =
            *reinterpret_cast<const uint4*>(g + ii * 8);
    }
    {
      const int d = t >> 1, c0 = (t & 1) * 32;
      const unsigned short* g = Vtrow + (size_t)d * S + k0 + c0;
#pragma unroll
      for (int ii = 0; ii < 4; ++ii)
        *reinterpret_cast<uint4*>(&Vts[d * VS_STR + c0 + ii * 8]) =
            *reinterpret_cast<const uint4*>(g + ii * 8);
    }
    __syncthreads();

    floatx4 sacc[2][4];
#pragma unroll
    for (int qg = 0; qg < 2; ++qg)
#pragma unroll
      for (int j = 0; j < 4; ++j) sacc[qg][j] = floatx4{0.f, 0.f, 0.f, 0.f};
#pragma unroll
    for (int j = 0; j < 4; ++j) {
      bf16x8 bk[4];
#pragma unroll
      for (int ks = 0; ks < 4; ++ks)
        bk[ks] = *reinterpret_cast<const bf16x8*>(
            &Ks[(j * 16 + l15) * KS_STR + ks * 32 + quad * 8]);
#pragma unroll
      for (int qg = 0; qg < 2; ++qg)
#pragma unroll
        for (int ks = 0; ks < 4; ++ks)
          sacc[qg][j] = __builtin_amdgcn_mfma_f32_16x16x32_bf16(
              aq[qg][ks], bk[ks], sacc[qg][j], 0, 0, 0);
    }

#pragma unroll
    for (int qg = 0; qg < 2; ++qg)
#pragma unroll
      for (int j = 0; j < 4; ++j) {
        const int ktg = k0 + j * 16 + l15;
#pragma unroll
        for (int r = 0; r < 4; ++r) {
          const float p =
              (ktg <= qrow[qg][r]) ? exp2f(sacc[qg][j][r]) : 0.0f;
          lpart[qg][r] += p;
          Ps[(w * 32 + qg * 16 + quad * 4 + r) * PS_STR + j * 16 + l15] =
              f32_to_bf16(p);
        }
      }

#pragma unroll
    for (int ks2 = 0; ks2 < 2; ++ks2) {
      bf16x8 ap[2];
#pragma unroll
      for (int qg = 0; qg < 2; ++qg)
        ap[qg] = *reinterpret_cast<const bf16x8*>(
            &Ps[(w * 32 + qg * 16 + l15) * PS_STR + ks2 * 32 + quad * 8]);
#pragma unroll
      for (int dj = 0; dj < 8; ++dj) {
        const bf16x8 bv = *reinterpret_cast<const bf16x8*>(
            &Vts[(dj * 16 + l15) * VS_STR + ks2 * 32 + quad * 8]);
#pragma unroll
        for (int qg = 0; qg < 2; ++qg)
          oacc[qg][dj] = __builtin_amdgcn_mfma_f32_16x16x32_bf16(
              ap[qg], bv, oacc[qg][dj], 0, 0, 0);
      }
    }
  }

#pragma unroll
  for (int qg = 0; qg < 2; ++qg)
#pragma unroll
    for (int r = 0; r < 4; ++r) {
      float l = lpart[qg][r];
      l += __shfl_xor(l, 1);
      l += __shfl_xor(l, 2);
      l += __shfl_xor(l, 4);
      l += __shfl_xor(l, 8);
      const float linv = 1.0f / l;
      unsigned short* orow =
          Orow + (size_t)(w * 32 + qg * 16 + quad * 4 + r) * H;
#pragma unroll
      for (int dj = 0; dj < 8; ++dj)
        orow[dj * 16 + l15] = f32_to_bf16(oacc[qg][dj][r] * linv);
    }
}

// ---------------------------------------------------------------------------
// Launch — round-0 structure (separate Q/K/V GEMM dispatches) + cast4 fusion
// ---------------------------------------------------------------------------
extern "C" void kernel_launch(void* const* d_in, const int* in_sizes, int n_in,
                              void* d_out, int out_size, void* d_ws,
                              size_t ws_size, hipStream_t stream) {
  const float* x  = (const float*)d_in[0];
  const float* Wq = (const float*)d_in[1];
  const float* bq = (const float*)d_in[2];
  const float* Wk = (const float*)d_in[3];
  const float* bk = (const float*)d_in[4];
  const float* Wv = (const float*)d_in[5];
  const float* bv = (const float*)d_in[6];
  const float* Wo = (const float*)d_in[7];
  const float* bo = (const float*)d_in[8];
  float* out = (float*)d_out;

  const int B = 2, S = 2048, H = 2048, nh = 16;
  const int M = B * S;  // 4096

  // workspace layout (~113 MB, no overlays)
  unsigned short* Wqb = (unsigned short*)d_ws;
  unsigned short* Wkb = Wqb + (size_t)H * H;
  unsigned short* Wvb = Wkb + (size_t)H * H;
  unsigned short* Wob = Wvb + (size_t)H * H;
  unsigned short* xb  = Wob + (size_t)H * H;
  unsigned short* Qbb = xb + (size_t)M * H;
  unsigned short* Kbb = Qbb + (size_t)M * H;
  unsigned short* Vtb = Kbb + (size_t)M * H;
  unsigned short* Ob  = Vtb + (size_t)M * H;
  float2* tab = (float2*)(Ob + (size_t)M * H);  // S*64 float2 = 1 MB

  const int cast_w4 = H * H / 4;
  const int cast_x4 = M * H / 4;
  const int tab_n = S * 64;

  rope_table_kernel<<<dim3(tab_n / 256), dim3(256), 0, stream>>>(tab, tab_n);
  cast_kernel<<<dim3(cast_x4 / 256), dim3(256), 0, stream>>>(x, xb, cast_x4);
  cast4_kernel<<<dim3(cast_w4 / 256, 4), dim3(256), 0, stream>>>(
      Wq, Wk, Wv, Wo, Wqb, Wkb, Wvb, Wob, cast_w4);

  dim3 ggrid(H / 128, M / 128);  // (16, 32) = 512 blocks, % 8 == 0
  const float qscale = 0.08838834764831845f * 1.4426950408889634f;

  gemm_fused<1><<<ggrid, dim3(256), 0, stream>>>(
      xb, Wqb, bq, nullptr, Qbb, tab, qscale, M, H, H, S);
  gemm_fused<1><<<ggrid, dim3(256), 0, stream>>>(
      xb, Wkb, bk, nullptr, Kbb, tab, 1.0f, M, H, H, S);
  gemm_fused<2><<<ggrid, dim3(256), 0, stream>>>(
      xb, Wvb, bv, nullptr, Vtb, nullptr, 1.0f, M, H, H, S);

  fattn_kernel<<<dim3((S / F_BQ) * B * nh), dim3(256), 0, stream>>>(
      Qbb, Kbb, Vtb, Ob, S, H, nh);

  gemm_fused<0><<<ggrid, dim3(256), 0, stream>>>(
      Ob, Wob, bo, out, nullptr, nullptr, 1.0f, M, H, H, S);
}

// Round 5
// 408.314 us; speedup vs baseline: 1.1591x; 1.0666x over previous
//
#include <hip/hip_runtime.h>
#include <math.h>

// ---------------------------------------------------------------------------
// Types / helpers
// ---------------------------------------------------------------------------
typedef __bf16 bf16x8 __attribute__((ext_vector_type(8)));
typedef float floatx4 __attribute__((ext_vector_type(4)));

__device__ __forceinline__ unsigned short f32_to_bf16(float f) {
  unsigned int u = __float_as_uint(f);
  u = u + 0x7FFFu + ((u >> 16) & 1u);   // RNE; inputs finite
  return (unsigned short)(u >> 16);
}
__device__ __forceinline__ float bf16_to_f32(unsigned short s) {
  return __uint_as_float(((unsigned int)s) << 16);
}

// async global->LDS, 16B per lane. lds base must be wave-uniform; HW scatters
// lane i to ldsbase + i*16  [m97 pattern].
__device__ __forceinline__ void gld_lds16(const unsigned short* g,
                                          unsigned short* l) {
  __builtin_amdgcn_global_load_lds(
      (const __attribute__((address_space(1))) unsigned int*)g,
      (__attribute__((address_space(3))) unsigned int*)l, 16, 0, 0);
}

// ---------------------------------------------------------------------------
// fp32 -> bf16 cast (vectorized float4 -> ushort4)
// ---------------------------------------------------------------------------
__global__ void cast_kernel(const float* __restrict__ in,
                            unsigned short* __restrict__ out, int n4) {
  int i = blockIdx.x * blockDim.x + threadIdx.x;
  if (i >= n4) return;
  const float4 v = reinterpret_cast<const float4*>(in)[i];
  ushort4 o;
  o.x = f32_to_bf16(v.x); o.y = f32_to_bf16(v.y);
  o.z = f32_to_bf16(v.z); o.w = f32_to_bf16(v.w);
  reinterpret_cast<ushort4*>(out)[i] = o;
}

// 4 equal-size weight casts in one dispatch (blockIdx.y selects buffer);
// per-element identical to cast_kernel (bit-exact, no shared writes).
__global__ void cast4_kernel(const float* __restrict__ a,
                             const float* __restrict__ b,
                             const float* __restrict__ c,
                             const float* __restrict__ d,
                             unsigned short* __restrict__ oa,
                             unsigned short* __restrict__ ob,
                             unsigned short* __restrict__ oc,
                             unsigned short* __restrict__ od, int n4) {
  int i = blockIdx.x * blockDim.x + threadIdx.x;
  if (i >= n4) return;
  const float* in;
  unsigned short* out;
  switch (blockIdx.y) {
    case 0: in = a; out = oa; break;
    case 1: in = b; out = ob; break;
    case 2: in = c; out = oc; break;
    default: in = d; out = od; break;
  }
  const float4 v = reinterpret_cast<const float4*>(in)[i];
  ushort4 o;
  o.x = f32_to_bf16(v.x); o.y = f32_to_bf16(v.y);
  o.z = f32_to_bf16(v.z); o.w = f32_to_bf16(v.w);
  reinterpret_cast<ushort4*>(out)[i] = o;
}

// ---------------------------------------------------------------------------
// RoPE cos/sin table: tab[s*64+i] = (cos, sin) of s / 10000^(i/64)
// ---------------------------------------------------------------------------
__global__ void rope_table_kernel(float2* __restrict__ tab, int total) {
  int idx = blockIdx.x * blockDim.x + threadIdx.x;
  if (idx >= total) return;
  const int s = idx >> 6, i = idx & 63;
  const float inv = powf(10000.0f, -(float)i * (1.0f / 64.0f));
  const float ang = (float)s * inv;
  tab[idx] = make_float2(cosf(ang), sinf(ang));
}

// ---------------------------------------------------------------------------
// Fused GEMM: C[m][n] = sum_k A[m][k]*B[n][k] + bias[n]
// 128x128 tile, BK=64, 4 waves, 4x4 16x16x32, XCD-aware block swizzle.
// EPI=0: fp32 out + bias (used for the O projection).
// ---------------------------------------------------------------------------
template <int EPI>
__global__ __launch_bounds__(256) void gemm_fused(
    const unsigned short* __restrict__ A, const unsigned short* __restrict__ B,
    const float* __restrict__ bias, float* __restrict__ Cf,
    unsigned short* __restrict__ Cb, const float2* __restrict__ tab,
    float scl, int M, int N, int K, int S) {
  __shared__ unsigned short As[128 * 64];
  __shared__ unsigned short Bs[128 * 64];
  const int t = threadIdx.x;
  const int lane = t & 63;
  const int w = t >> 6;

  // XCD swizzle: contiguous tile range per XCD (requires nwg % 8 == 0).
  const int nwg = gridDim.x * gridDim.y;       // 512 here
  const int orig = blockIdx.y * gridDim.x + blockIdx.x;
  const int wgid = (orig & 7) * (nwg >> 3) + (orig >> 3);
  const int bm = (wgid / gridDim.x) * 128;
  const int bn = (wgid % gridDim.x) * 128;

  const int wm = (w & 1) * 64;
  const int wn = (w >> 1) * 64;
  const int m16 = lane & 15;
  const int quad = lane >> 4;
  const int key = m16 & 7;

  const int lr = lane >> 3;
  const int lc = ((lane & 7) ^ lr) * 8;

  floatx4 acc[4][4];
#pragma unroll
  for (int i = 0; i < 4; ++i)
#pragma unroll
    for (int j = 0; j < 4; ++j) acc[i][j] = floatx4{0.f, 0.f, 0.f, 0.f};

  const unsigned short* Abase = A + (size_t)(bm + w * 32 + lr) * K + lc;
  const unsigned short* Bbase = B + (size_t)(bn + w * 32 + lr) * K + lc;

  for (int k0 = 0; k0 < K; k0 += 64) {
    __syncthreads();  // previous-iter readers done before overwrite
#pragma unroll
    for (int it = 0; it < 4; ++it) {
      gld_lds16(Abase + (size_t)it * 8 * K + k0, &As[(w * 4 + it) * 512]);
      gld_lds16(Bbase + (size_t)it * 8 * K + k0, &Bs[(w * 4 + it) * 512]);
    }
    __syncthreads();  // drains vmcnt(0): LDS data visible
#pragma unroll
    for (int ks = 0; ks < 64; ks += 32) {
      const int ck = ks >> 3;  // 0 or 4
      bf16x8 af[4], bfr[4];
#pragma unroll
      for (int i = 0; i < 4; ++i)
        af[i] = *reinterpret_cast<const bf16x8*>(
            &As[(wm + i * 16 + m16) * 64 + ((ck | quad) ^ key) * 8]);
#pragma unroll
      for (int j = 0; j < 4; ++j)
        bfr[j] = *reinterpret_cast<const bf16x8*>(
            &Bs[(wn + j * 16 + m16) * 64 + ((ck | quad) ^ key) * 8]);
#pragma unroll
      for (int i = 0; i < 4; ++i)
#pragma unroll
        for (int j = 0; j < 4; ++j)
          acc[i][j] = __builtin_amdgcn_mfma_f32_16x16x32_bf16(
              af[i], bfr[j], acc[i][j], 0, 0, 0);
    }
  }

  // epilogue: C/D layout col=lane&15, row=quad*4+reg  [m89/m91 verified]
#pragma unroll
  for (int i = 0; i < 4; ++i) {
    const int rbase = bm + wm + i * 16 + quad * 4;
#pragma unroll
    for (int j = 0; j < 4; ++j) {
      const int col = bn + wn + j * 16 + m16;
      const float bv = bias[col];
      if (EPI == 0) {
#pragma unroll
        for (int r = 0; r < 4; ++r)
          Cf[(size_t)(rbase + r) * N + col] = acc[i][j][r] + bv;
      }
    }
  }
}

// ---------------------------------------------------------------------------
// QKV fused projection: one dispatch, blockIdx.z in {0,1,2} selects
// {Wq->Q(RoPE,scaled), Wk->K(RoPE), Wv->Vt(transposed bf16)}. 1536 blocks
// (~4 resident/CU) so one block's barrier-drain stall hides under another's
// compute. Measured (round 1): ~30 us vs 3 separate dispatches; deterministic
// absmax 0.0645 (FMA-contraction codegen differs from gemm_fused<1>).
// Per-z-slice XCD swizzle: pure block->tile permutation, output-invariant.
// ---------------------------------------------------------------------------
__global__ __launch_bounds__(256) void gemm_qkv(
    const unsigned short* __restrict__ A, const unsigned short* __restrict__ Bq,
    const unsigned short* __restrict__ Bk, const unsigned short* __restrict__ Bv,
    const float* __restrict__ biasq, const float* __restrict__ biask,
    const float* __restrict__ biasv, unsigned short* __restrict__ Qb,
    unsigned short* __restrict__ Kb, unsigned short* __restrict__ Vtb,
    const float2* __restrict__ tab, float qscale, int M, int N, int K, int S) {
  __shared__ unsigned short As[128 * 64];
  __shared__ unsigned short Bs[128 * 64];
  const int t = threadIdx.x;
  const int lane = t & 63;
  const int w = t >> 6;
  const int z = blockIdx.z;

  // XCD swizzle within the z-slice (512 blocks, % 8 == 0)
  const int nwg = gridDim.x * gridDim.y;
  const int orig = blockIdx.y * gridDim.x + blockIdx.x;
  const int wgid = (orig & 7) * (nwg >> 3) + (orig >> 3);
  const int bm = (wgid / gridDim.x) * 128;
  const int bn = (wgid % gridDim.x) * 128;

  const int wm = (w & 1) * 64;
  const int wn = (w >> 1) * 64;
  const int m16 = lane & 15;
  const int quad = lane >> 4;
  const int key = m16 & 7;

  const int lr = lane >> 3;
  const int lc = ((lane & 7) ^ lr) * 8;

  const unsigned short* B = (z == 0) ? Bq : ((z == 1) ? Bk : Bv);
  const float* bias = (z == 0) ? biasq : ((z == 1) ? biask : biasv);
  unsigned short* Cb = (z == 0) ? Qb : ((z == 1) ? Kb : Vtb);
  const float scl = (z == 0) ? qscale : 1.0f;

  floatx4 acc[4][4];
#pragma unroll
  for (int i = 0; i < 4; ++i)
#pragma unroll
    for (int j = 0; j < 4; ++j) acc[i][j] = floatx4{0.f, 0.f, 0.f, 0.f};

  const unsigned short* Abase = A + (size_t)(bm + w * 32 + lr) * K + lc;
  const unsigned short* Bbase = B + (size_t)(bn + w * 32 + lr) * K + lc;

  for (int k0 = 0; k0 < K; k0 += 64) {
    __syncthreads();
#pragma unroll
    for (int it = 0; it < 4; ++it) {
      gld_lds16(Abase + (size_t)it * 8 * K + k0, &As[(w * 4 + it) * 512]);
      gld_lds16(Bbase + (size_t)it * 8 * K + k0, &Bs[(w * 4 + it) * 512]);
    }
    __syncthreads();
#pragma unroll
    for (int ks = 0; ks < 64; ks += 32) {
      const int ck = ks >> 3;
      bf16x8 af[4], bfr[4];
#pragma unroll
      for (int i = 0; i < 4; ++i)
        af[i] = *reinterpret_cast<const bf16x8*>(
            &As[(wm + i * 16 + m16) * 64 + ((ck | quad) ^ key) * 8]);
#pragma unroll
      for (int j = 0; j < 4; ++j)
        bfr[j] = *reinterpret_cast<const bf16x8*>(
            &Bs[(wn + j * 16 + m16) * 64 + ((ck | quad) ^ key) * 8]);
#pragma unroll
      for (int i = 0; i < 4; ++i)
#pragma unroll
        for (int j = 0; j < 4; ++j)
          acc[i][j] = __builtin_amdgcn_mfma_f32_16x16x32_bf16(
              af[i], bfr[j], acc[i][j], 0, 0, 0);
    }
  }

  // epilogue: C/D layout col=lane&15, row=quad*4+reg  [m89/m91 verified]
#pragma unroll
  for (int i = 0; i < 4; ++i) {
    const int rbase = bm + wm + i * 16 + quad * 4;
#pragma unroll
    for (int j = 0; j < 4; ++j) {
      const int col = bn + wn + j * 16 + m16;
      const float bvv = bias[col];
      if (z != 2) {  // RoPE (interleaved pairs) -> bf16, scaled
        const int pi = (col & 127) >> 1;
#pragma unroll
        for (int r = 0; r < 4; ++r) {
          const int row = rbase + r;
          const int s = row & (S - 1);
          const float v = acc[i][j][r] + bvv;
          const float vp = __shfl_xor(v, 1);
          const float2 cs = tab[s * 64 + pi];
          const float oe = (v * cs.x - vp * cs.y) * scl;
          const float oo = (vp * cs.x + v * cs.y) * scl;
          if ((m16 & 1) == 0) {
            const unsigned pk =
                (unsigned)f32_to_bf16(oe) | ((unsigned)f32_to_bf16(oo) << 16);
            *reinterpret_cast<unsigned*>(Cb + (size_t)row * N + col) = pk;
          }
        }
      } else {  // transposed bf16 V: Vt[(b*2048 + col)][s]
        const int b = rbase >> 11;           // S = 2048
        const int s = rbase & (S - 1);       // multiple of 4
        ushort4 pk;
        pk.x = f32_to_bf16(acc[i][j][0] + bvv);
        pk.y = f32_to_bf16(acc[i][j][1] + bvv);
        pk.z = f32_to_bf16(acc[i][j][2] + bvv);
        pk.w = f32_to_bf16(acc[i][j][3] + bvv);
        *reinterpret_cast<ushort4*>(
            Cb + ((size_t)((b << 11) + col)) * S + s) = pk;
      }
    }
  }
}

// ---------------------------------------------------------------------------
// MFMA flash attention — VERBATIM round-0 kernel (verified: 96 us, bit-exact
// component). DMA/prefetch variants are banned (R2/R3 added real numeric
// error on top of qkv's contraction drift).
// ---------------------------------------------------------------------------
constexpr int F_BQ = 128, F_BK = 64, F_DH = 128;
constexpr int KS_STR = 136;
constexpr int VS_STR = 72;
constexpr int PS_STR = 72;

__global__ __launch_bounds__(256, 2) void fattn_kernel(
    const unsigned short* __restrict__ Qb, const unsigned short* __restrict__ Kb,
    const unsigned short* __restrict__ Vtb, unsigned short* __restrict__ Ob,
    int S, int H, int nh) {
  __shared__ unsigned short Ks[F_BK * KS_STR];
  __shared__ unsigned short Vts[F_DH * VS_STR];
  __shared__ unsigned short Ps[F_BQ * PS_STR];

  const int t = threadIdx.x;
  const int lane = t & 63;
  const int w = t >> 6;
  const int l15 = lane & 15;
  const int quad = lane >> 4;

  const int i = blockIdx.x;
  const int bh = i & 31;
  const int qt = (i < 256) ? (i >> 5) : (15 - ((i - 256) >> 5));
  const int h = bh & 15;
  const int b = bh >> 4;
  const int q0 = qt * F_BQ;

  const unsigned short* Qrow = Qb + ((size_t)(b * S + q0)) * H + h * F_DH;
  const unsigned short* Krow = Kb + ((size_t)b * S) * H + h * F_DH;
  const unsigned short* Vtrow = Vtb + ((size_t)bh * F_DH) * S;
  unsigned short* Orow = Ob + ((size_t)(b * S + q0)) * H + h * F_DH;

  bf16x8 aq[2][4];
#pragma unroll
  for (int qg = 0; qg < 2; ++qg)
#pragma unroll
    for (int ks = 0; ks < 4; ++ks)
      aq[qg][ks] = *reinterpret_cast<const bf16x8*>(
          Qrow + (size_t)(w * 32 + qg * 16 + l15) * H + ks * 32 + quad * 8);

  floatx4 oacc[2][8];
#pragma unroll
  for (int qg = 0; qg < 2; ++qg)
#pragma unroll
    for (int dj = 0; dj < 8; ++dj) oacc[qg][dj] = floatx4{0.f, 0.f, 0.f, 0.f};
  float lpart[2][4] = {{0.f, 0.f, 0.f, 0.f}, {0.f, 0.f, 0.f, 0.f}};
  int qrow[2][4];
#pragma unroll
  for (int qg = 0; qg < 2; ++qg)
#pragma unroll
    for (int r = 0; r < 4; ++r)
      qrow[qg][r] = q0 + w * 32 + qg * 16 + quad * 4 + r;

  const int ntile = q0 / F_BK + 2;
  for (int tile = 0; tile < ntile; ++tile) {
    const int k0 = tile * F_BK;
    __syncthreads();
    {
      const int kt = t >> 2, c0 = (t & 3) * 32;
      const unsigned short* g = Krow + (size_t)(k0 + kt) * H + c0;
#pragma unroll
      for (int ii = 0; ii < 4; ++ii)
        *reinterpret_cast<uint4*>(&Ks[kt * KS_STR + c0 + ii * 8]) =
            *reinterpret_cast<const uint4*>(g + ii * 8);
    }
    {
      const int d = t >> 1, c0 = (t & 1) * 32;
      const unsigned short* g = Vtrow + (size_t)d * S + k0 + c0;
#pragma unroll
      for (int ii = 0; ii < 4; ++ii)
        *reinterpret_cast<uint4*>(&Vts[d * VS_STR + c0 + ii * 8]) =
            *reinterpret_cast<const uint4*>(g + ii * 8);
    }
    __syncthreads();

    floatx4 sacc[2][4];
#pragma unroll
    for (int qg = 0; qg < 2; ++qg)
#pragma unroll
      for (int j = 0; j < 4; ++j) sacc[qg][j] = floatx4{0.f, 0.f, 0.f, 0.f};
#pragma unroll
    for (int j = 0; j < 4; ++j) {
      bf16x8 bk[4];
#pragma unroll
      for (int ks = 0; ks < 4; ++ks)
        bk[ks] = *reinterpret_cast<const bf16x8*>(
            &Ks[(j * 16 + l15) * KS_STR + ks * 32 + quad * 8]);
#pragma unroll
      for (int qg = 0; qg < 2; ++qg)
#pragma unroll
        for (int ks = 0; ks < 4; ++ks)
          sacc[qg][j] = __builtin_amdgcn_mfma_f32_16x16x32_bf16(
              aq[qg][ks], bk[ks], sacc[qg][j], 0, 0, 0);
    }

#pragma unroll
    for (int qg = 0; qg < 2; ++qg)
#pragma unroll
      for (int j = 0; j < 4; ++j) {
        const int ktg = k0 + j * 16 + l15;
#pragma unroll
        for (int r = 0; r < 4; ++r) {
          const float p =
              (ktg <= qrow[qg][r]) ? exp2f(sacc[qg][j][r]) : 0.0f;
          lpart[qg][r] += p;
          Ps[(w * 32 + qg * 16 + quad * 4 + r) * PS_STR + j * 16 + l15] =
              f32_to_bf16(p);
        }
      }

#pragma unroll
    for (int ks2 = 0; ks2 < 2; ++ks2) {
      bf16x8 ap[2];
#pragma unroll
      for (int qg = 0; qg < 2; ++qg)
        ap[qg] = *reinterpret_cast<const bf16x8*>(
            &Ps[(w * 32 + qg * 16 + l15) * PS_STR + ks2 * 32 + quad * 8]);
#pragma unroll
      for (int dj = 0; dj < 8; ++dj) {
        const bf16x8 bv = *reinterpret_cast<const bf16x8*>(
            &Vts[(dj * 16 + l15) * VS_STR + ks2 * 32 + quad * 8]);
#pragma unroll
        for (int qg = 0; qg < 2; ++qg)
          oacc[qg][dj] = __builtin_amdgcn_mfma_f32_16x16x32_bf16(
              ap[qg], bv, oacc[qg][dj], 0, 0, 0);
      }
    }
  }

#pragma unroll
  for (int qg = 0; qg < 2; ++qg)
#pragma unroll
    for (int r = 0; r < 4; ++r) {
      float l = lpart[qg][r];
      l += __shfl_xor(l, 1);
      l += __shfl_xor(l, 2);
      l += __shfl_xor(l, 4);
      l += __shfl_xor(l, 8);
      const float linv = 1.0f / l;
      unsigned short* orow =
          Orow + (size_t)(w * 32 + qg * 16 + quad * 4 + r) * H;
#pragma unroll
      for (int dj = 0; dj < 8; ++dj)
        orow[dj * 16 + l15] = f32_to_bf16(oacc[qg][dj][r] * linv);
    }
}

// ---------------------------------------------------------------------------
// Launch
// ---------------------------------------------------------------------------
extern "C" void kernel_launch(void* const* d_in, const int* in_sizes, int n_in,
                              void* d_out, int out_size, void* d_ws,
                              size_t ws_size, hipStream_t stream) {
  const float* x  = (const float*)d_in[0];
  const float* Wq = (const float*)d_in[1];
  const float* bq = (const float*)d_in[2];
  const float* Wk = (const float*)d_in[3];
  const float* bk = (const float*)d_in[4];
  const float* Wv = (const float*)d_in[5];
  const float* bv = (const float*)d_in[6];
  const float* Wo = (const float*)d_in[7];
  const float* bo = (const float*)d_in[8];
  float* out = (float*)d_out;

  const int B = 2, S = 2048, H = 2048, nh = 16;
  const int M = B * S;  // 4096

  // workspace layout (~113 MB, no overlays)
  unsigned short* Wqb = (unsigned short*)d_ws;
  unsigned short* Wkb = Wqb + (size_t)H * H;
  unsigned short* Wvb = Wkb + (size_t)H * H;
  unsigned short* Wob = Wvb + (size_t)H * H;
  unsigned short* xb  = Wob + (size_t)H * H;
  unsigned short* Qbb = xb + (size_t)M * H;
  unsigned short* Kbb = Qbb + (size_t)M * H;
  unsigned short* Vtb = Kbb + (size_t)M * H;
  unsigned short* Ob  = Vtb + (size_t)M * H;
  float2* tab = (float2*)(Ob + (size_t)M * H);  // S*64 float2 = 1 MB

  const int cast_w4 = H * H / 4;
  const int cast_x4 = M * H / 4;
  const int tab_n = S * 64;

  rope_table_kernel<<<dim3(tab_n / 256), dim3(256), 0, stream>>>(tab, tab_n);
  cast_kernel<<<dim3(cast_x4 / 256), dim3(256), 0, stream>>>(x, xb, cast_x4);
  cast4_kernel<<<dim3(cast_w4 / 256, 4), dim3(256), 0, stream>>>(
      Wq, Wk, Wv, Wo, Wqb, Wkb, Wvb, Wob, cast_w4);

  const float qscale = 0.08838834764831845f * 1.4426950408889634f;

  // Q, K, V projections in ONE dispatch: (16, 32, 3) = 1536 blocks
  gemm_qkv<<<dim3(H / 128, M / 128, 3), dim3(256), 0, stream>>>(
      xb, Wqb, Wkb, Wvb, bq, bk, bv, Qbb, Kbb, Vtb, tab, qscale, M, H, H, S);

  fattn_kernel<<<dim3((S / F_BQ) * B * nh), dim3(256), 0, stream>>>(
      Qbb, Kbb, Vtb, Ob, S, H, nh);

  gemm_fused<0><<<dim3(H / 128, M / 128), dim3(256), 0, stream>>>(
      Ob, Wob, bo, out, nullptr, nullptr, 1.0f, M, H, H, S);
}